// Round 1
// baseline (869.466 us; speedup 1.0000x reference)
//
#include <hip/hip_runtime.h>

#define T_TOK 2048
#define H_DIM 1024
#define E_NUM 64
#define TOPK  6
#define I_DIM 512
#define SI_DIM 1024
#define CAP   512   // max tokens per expert we support (avg is 192, max ~240)

typedef __attribute__((ext_vector_type(8))) short bf16x8;
typedef __attribute__((ext_vector_type(4))) float f32x4;
typedef __attribute__((ext_vector_type(4))) short short4v;

__device__ __forceinline__ short f2bf(float f) {
  union { float f; unsigned u; } v; v.f = f;
  unsigned r = v.u + 0x7FFFu + ((v.u >> 16) & 1u);  // RNE
  return (short)(r >> 16);
}

// ---------------- x -> bf16 ----------------
__global__ __launch_bounds__(256) void cvt_kernel(const float* __restrict__ x,
                                                  short* __restrict__ xb) {
  int i = (blockIdx.x * 256 + threadIdx.x) * 4;
  float4 v = *(const float4*)(x + i);
  short4v o;
  o[0] = f2bf(v.x); o[1] = f2bf(v.y); o[2] = f2bf(v.z); o[3] = f2bf(v.w);
  *(short4v*)(xb + i) = o;
}

__global__ void zero_cnt(int* __restrict__ cnt) {
  if (threadIdx.x < E_NUM) cnt[threadIdx.x] = 0;
}

// ---------------- router: scores = sigmoid(x @ gate_w^T), exact fp32 ----------------
__global__ __launch_bounds__(256) void router_kernel(const float* __restrict__ x,
                                                     const float* __restrict__ gw,
                                                     float* __restrict__ scores) {
  int t = blockIdx.x * 4 + (threadIdx.x >> 6);
  int e = threadIdx.x & 63;
  const float4* xr = (const float4*)(x + (size_t)t * H_DIM);
  const float4* wr = (const float4*)(gw + (size_t)e * H_DIM);
  float s = 0.f;
  #pragma unroll 4
  for (int i = 0; i < H_DIM / 4; i++) {
    float4 a = xr[i], b = wr[i];
    s = fmaf(a.x, b.x, s); s = fmaf(a.y, b.y, s);
    s = fmaf(a.z, b.z, s); s = fmaf(a.w, b.w, s);
  }
  scores[t * E_NUM + e] = 1.f / (1.f + __expf(-s));
}

// ---------------- top-k per token, build per-expert token lists ----------------
__global__ __launch_bounds__(64) void topk_kernel(const float* __restrict__ scores,
                                                  const float* __restrict__ bias,
                                                  int* __restrict__ cnt,
                                                  int* __restrict__ tokens,
                                                  float* __restrict__ wts) {
  int t = blockIdx.x;
  int e = threadIdx.x;          // one lane per expert, 64 lanes
  float s = scores[t * E_NUM + e];
  float c = s + bias[e];        // selection on bias-corrected
  int selected = 0;
  float sum = 0.f;
  for (int k = 0; k < TOPK; k++) {
    float v = c; int idx = e;
    #pragma unroll
    for (int off = 32; off > 0; off >>= 1) {
      float v2 = __shfl_xor(v, off);
      int  i2 = __shfl_xor(idx, off);
      if (v2 > v || (v2 == v && i2 < idx)) { v = v2; idx = i2; }
    }
    sum += __shfl(s, idx);      // uncorrected score of winner
    if (e == idx) { selected = 1; c = -__builtin_inff(); }
  }
  if (selected) {
    int pos = atomicAdd(&cnt[e], 1);
    if (pos < CAP) {
      tokens[e * CAP + pos] = t;
      wts[e * CAP + pos] = s / sum;   // renormalized, uncorrected
    }
  }
}

// ---------------- B-fragment direct load (fp32 -> bf16) ----------------
template<int LDB>
__device__ __forceinline__ bf16x8 load_bfrag(const float* __restrict__ p) {
  bf16x8 b;
  #pragma unroll
  for (int j = 0; j < 8; j++) b[j] = f2bf(p[(size_t)j * LDB]);
  return b;
}

// ---------------- fused gate+up GEMM + SwiGLU (+routing weight) ----------------
// Block: 256 thr = 4 waves. M_TILE=64, N_TILE=128 (per wave 32 cols), K-loop step 32.
// MOE=1: rows gathered via tokens list; MOE=0: dense rows (shared expert).
template<int MOE, int LDB>
__global__ __launch_bounds__(256) void gu_kernel(
    const short* __restrict__ Xb, const float* __restrict__ Wg,
    const float* __restrict__ Wu, short* __restrict__ Out,
    const int* __restrict__ tokens, const float* __restrict__ wts,
    const int* __restrict__ cnt, int Kd, int outLd)
{
  const int e  = blockIdx.z;
  const int m0 = blockIdx.y * 64;
  const int n0 = blockIdx.x * 128;
  int count = 1 << 30;
  const int* tlist = tokens;
  const float* wlist = wts;
  if (MOE) {
    int c = cnt[e]; if (c > CAP) c = CAP;
    count = c;
    if (m0 >= count) return;
    tlist = tokens + e * CAP;
    wlist = wts + e * CAP;
  }
  const int lane = threadIdx.x & 63;
  const int wave = threadIdx.x >> 6;
  const int quad = lane >> 4;
  const int l16  = lane & 15;
  const int ncol = n0 + wave * 32;

  const size_t wOff = MOE ? (size_t)e * Kd * LDB : 0;
  const float* wg0 = Wg + wOff + (size_t)(quad * 8) * LDB + ncol + l16;
  const float* wu0 = Wu + wOff + (size_t)(quad * 8) * LDB + ncol + l16;

  const short* arow[4];
  #pragma unroll
  for (int mt = 0; mt < 4; mt++) {
    int gr = m0 + mt * 16 + l16;
    int trow;
    if (MOE) trow = (gr < count) ? tlist[gr] : tlist[0];
    else     trow = gr;
    arow[mt] = Xb + (size_t)trow * Kd + quad * 8;
  }

  f32x4 accg[2][4], accu[2][4];
  #pragma unroll
  for (int i = 0; i < 2; i++)
    #pragma unroll
    for (int j = 0; j < 4; j++) {
      accg[i][j] = (f32x4){0.f, 0.f, 0.f, 0.f};
      accu[i][j] = (f32x4){0.f, 0.f, 0.f, 0.f};
    }

  const int kSteps = Kd >> 5;
  for (int kb = 0; kb < kSteps; kb++) {
    bf16x8 a[4];
    #pragma unroll
    for (int mt = 0; mt < 4; mt++)
      a[mt] = *(const bf16x8*)(arow[mt] + kb * 32);
    #pragma unroll
    for (int nst = 0; nst < 2; nst++) {
      const float* pg = wg0 + (size_t)(kb * 32) * LDB + nst * 16;
      const float* pu = wu0 + (size_t)(kb * 32) * LDB + nst * 16;
      bf16x8 bg = load_bfrag<LDB>(pg);
      bf16x8 bu = load_bfrag<LDB>(pu);
      #pragma unroll
      for (int mt = 0; mt < 4; mt++) {
        accg[nst][mt] = __builtin_amdgcn_mfma_f32_16x16x32_bf16(a[mt], bg, accg[nst][mt], 0, 0, 0);
        accu[nst][mt] = __builtin_amdgcn_mfma_f32_16x16x32_bf16(a[mt], bu, accu[nst][mt], 0, 0, 0);
      }
    }
  }

  const int outRow0 = (MOE ? e * CAP : 0) + m0;
  #pragma unroll
  for (int mt = 0; mt < 4; mt++) {
    #pragma unroll
    for (int reg = 0; reg < 4; reg++) {
      int lr = mt * 16 + quad * 4 + reg;   // local row; C/D: row=quad*4+reg, col=l16
      if (MOE && (m0 + lr) >= count) continue;
      float wt = MOE ? wlist[m0 + lr] : 1.f;
      size_t orow = (size_t)(outRow0 + lr) * outLd;
      #pragma unroll
      for (int nst = 0; nst < 2; nst++) {
        float g = accg[nst][mt][reg];
        float u = accu[nst][mt][reg];
        float hval = (g / (1.f + __expf(-g))) * u * wt;   // silu(g)*u*w
        Out[orow + ncol + nst * 16 + l16] = f2bf(hval);
      }
    }
  }
}

// ---------------- down-projection GEMM ----------------
// MOE=1: A = Hbuf (gathered rows), scatter atomicAdd into out[token].
// MOE=0: A = Hs (dense), plain store (initializes out with shared-expert result).
template<int MOE, int LDB>
__global__ __launch_bounds__(256) void down_kernel(
    const short* __restrict__ Ab, const float* __restrict__ Wd,
    float* __restrict__ Out, const int* __restrict__ tokens,
    const int* __restrict__ cnt, int Kd)
{
  const int e  = blockIdx.z;
  const int m0 = blockIdx.y * 64;
  const int n0 = blockIdx.x * 128;
  int count = 1 << 30;
  const int* tlist = tokens;
  if (MOE) {
    int c = cnt[e]; if (c > CAP) c = CAP;
    count = c;
    if (m0 >= count) return;
    tlist = tokens + e * CAP;
  }
  const int lane = threadIdx.x & 63;
  const int wave = threadIdx.x >> 6;
  const int quad = lane >> 4;
  const int l16  = lane & 15;
  const int ncol = n0 + wave * 32;

  const float* wd0 = Wd + (MOE ? (size_t)e * Kd * LDB : 0)
                        + (size_t)(quad * 8) * LDB + ncol + l16;
  const short* abase = Ab + (MOE ? (size_t)(e * CAP) * Kd : 0);

  const short* arow[4];
  #pragma unroll
  for (int mt = 0; mt < 4; mt++)
    arow[mt] = abase + (size_t)(m0 + mt * 16 + l16) * Kd + quad * 8;

  f32x4 acc[2][4];
  #pragma unroll
  for (int i = 0; i < 2; i++)
    #pragma unroll
    for (int j = 0; j < 4; j++) acc[i][j] = (f32x4){0.f, 0.f, 0.f, 0.f};

  const int kSteps = Kd >> 5;
  for (int kb = 0; kb < kSteps; kb++) {
    bf16x8 a[4];
    #pragma unroll
    for (int mt = 0; mt < 4; mt++)
      a[mt] = *(const bf16x8*)(arow[mt] + kb * 32);
    #pragma unroll
    for (int nst = 0; nst < 2; nst++) {
      bf16x8 b = load_bfrag<LDB>(wd0 + (size_t)(kb * 32) * LDB + nst * 16);
      #pragma unroll
      for (int mt = 0; mt < 4; mt++)
        acc[nst][mt] = __builtin_amdgcn_mfma_f32_16x16x32_bf16(a[mt], b, acc[nst][mt], 0, 0, 0);
    }
  }

  #pragma unroll
  for (int mt = 0; mt < 4; mt++) {
    #pragma unroll
    for (int reg = 0; reg < 4; reg++) {
      int lr = mt * 16 + quad * 4 + reg;
      if (MOE && (m0 + lr) >= count) continue;
      int trow = MOE ? tlist[m0 + lr] : (m0 + lr);
      float* op = Out + (size_t)trow * H_DIM + ncol + l16;
      #pragma unroll
      for (int nst = 0; nst < 2; nst++) {
        float v = acc[nst][mt][reg];
        if (MOE) atomicAdd(op + nst * 16, v);
        else     op[nst * 16] = v;
      }
    }
  }
}

// ---------------- launch ----------------
extern "C" void kernel_launch(void* const* d_in, const int* in_sizes, int n_in,
                              void* d_out, int out_size, void* d_ws, size_t ws_size,
                              hipStream_t stream) {
  (void)in_sizes; (void)n_in; (void)out_size; (void)ws_size;
  const float* x       = (const float*)d_in[0];
  const float* gate_w  = (const float*)d_in[1];
  const float* gate_b  = (const float*)d_in[2];
  const float* w_gate  = (const float*)d_in[3];
  const float* w_up    = (const float*)d_in[4];
  const float* w_down  = (const float*)d_in[5];
  const float* ws_gate = (const float*)d_in[6];
  const float* ws_up   = (const float*)d_in[7];
  const float* ws_down = (const float*)d_in[8];
  float* out = (float*)d_out;

  char* p = (char*)d_ws;
  auto alloc = [&](size_t bytes) {
    char* r = p; p += (bytes + 255) & ~(size_t)255; return r;
  };
  float* scores = (float*)alloc((size_t)T_TOK * E_NUM * 4);
  int*   cnt    = (int*)  alloc(E_NUM * 4);
  int*   tokens = (int*)  alloc((size_t)E_NUM * CAP * 4);
  float* wts    = (float*)alloc((size_t)E_NUM * CAP * 4);
  short* xb     = (short*)alloc((size_t)T_TOK * H_DIM * 2);
  short* Hs     = (short*)alloc((size_t)T_TOK * SI_DIM * 2);
  short* Hbuf   = (short*)alloc((size_t)E_NUM * CAP * I_DIM * 2);

  cvt_kernel<<<T_TOK * H_DIM / 1024, 256, 0, stream>>>(x, xb);
  zero_cnt<<<1, 64, 0, stream>>>(cnt);
  router_kernel<<<T_TOK / 4, 256, 0, stream>>>(x, gate_w, scores);
  topk_kernel<<<T_TOK, 64, 0, stream>>>(scores, gate_b, cnt, tokens, wts);

  // shared expert: gate/up -> Hs (bf16), then down -> writes out
  gu_kernel<0, SI_DIM><<<dim3(SI_DIM / 128, T_TOK / 64, 1), 256, 0, stream>>>(
      xb, ws_gate, ws_up, Hs, nullptr, nullptr, nullptr, H_DIM, SI_DIM);
  // MoE experts: gate/up -> Hbuf (bf16, weighted)
  gu_kernel<1, I_DIM><<<dim3(I_DIM / 128, CAP / 64, E_NUM), 256, 0, stream>>>(
      xb, w_gate, w_up, Hbuf, tokens, wts, cnt, H_DIM, I_DIM);
  // shared down writes out (full coverage), then MoE down accumulates atomically
  down_kernel<0, H_DIM><<<dim3(H_DIM / 128, T_TOK / 64, 1), 256, 0, stream>>>(
      Hs, ws_down, out, nullptr, nullptr, SI_DIM);
  down_kernel<1, H_DIM><<<dim3(H_DIM / 128, CAP / 64, E_NUM), 256, 0, stream>>>(
      Hbuf, w_down, out, tokens, cnt, I_DIM);
}